// Round 2
// baseline (271.819 us; speedup 1.0000x reference)
//
#include <hip/hip_runtime.h>
#include <math.h>

#define BB 32
#define SS 4096
#define DD 1024
#define CHUNKS 64                      // S-chunks per batch
#define ROWS_PER_CHUNK (SS / CHUNKS)   // 64
#define NBLK2 (BB * CHUNKS)            // 2048

typedef float vf4 __attribute__((ext_vector_type(4)));

__device__ __forceinline__ float wave_reduce_sum(float v) {
    #pragma unroll
    for (int off = 32; off > 0; off >>= 1)
        v += __shfl_xor(v, off, 64);
    return v;
}

__device__ __forceinline__ float dot4v(vf4 a, vf4 b) {
    return a.x * b.x + a.y * b.y + a.z * b.z + a.w * b.w;
}

// K1: dec_att[b,d] = sum_k dec[b,k] * Win[d,k]   (x @ W.T)
__global__ __launch_bounds__(256) void k1_decatt(const float* __restrict__ dec,
                                                 const float* __restrict__ Win,
                                                 float* __restrict__ dec_att) {
    const int wid = threadIdx.x >> 6, lane = threadIdx.x & 63;
    const int d = blockIdx.x * 4 + wid;          // 256 blocks -> 1024 d
    const vf4* Wrow = (const vf4*)(Win + (size_t)d * DD);
    vf4 w4[4];
    #pragma unroll
    for (int i = 0; i < 4; ++i) w4[i] = Wrow[lane + i * 64];
    #pragma unroll 2
    for (int b = 0; b < BB; ++b) {
        const vf4* x = (const vf4*)(dec + (size_t)b * DD);
        float p = 0.f;
        #pragma unroll
        for (int i = 0; i < 4; ++i) p += dot4v(w4[i], x[lane + i * 64]);
        p = wave_reduce_sum(p);
        if (lane == 0) dec_att[(size_t)b * DD + d] = p;
    }
}

// K2: single-pass online-softmax scan over enc rows, register double-buffered.
__global__ __launch_bounds__(256, 4) void k2_scan(const float* __restrict__ enc,
                                                  const float* __restrict__ dec_att,
                                                  float* __restrict__ scores,
                                                  float* __restrict__ pacc,
                                                  float* __restrict__ pml) {
    const int wid = threadIdx.x >> 6, lane = threadIdx.x & 63;
    const int b = blockIdx.x / CHUNKS, chunk = blockIdx.x % CHUNKS;
    const int s0 = chunk * ROWS_PER_CHUNK;

    const vf4* q = (const vf4*)(dec_att + (size_t)b * DD);
    vf4 q4[4];
    #pragma unroll
    for (int i = 0; i < 4; ++i) q4[i] = q[lane + i * 64];

    const vf4* encb = (const vf4*)(enc + ((size_t)b * SS + s0) * DD);

    float m = -1e30f, l = 0.f, msc = 0.f;
    vf4 a4[4];
    #pragma unroll
    for (int i = 0; i < 4; ++i) a4[i] = (vf4)(0.f);

    vf4 eA[4], eB[4];
    {   // prefetch row for k=0
        const vf4* row = encb + (size_t)wid * (DD / 4);
        #pragma unroll
        for (int i = 0; i < 4; ++i) eA[i] = __builtin_nontemporal_load(&row[lane + i * 64]);
    }

    #pragma unroll
    for (int k = 0; k < 16; k += 2) {
        {   // prefetch row k+1 into eB
            const vf4* row = encb + (size_t)(wid + 4 * (k + 1)) * (DD / 4);
            #pragma unroll
            for (int i = 0; i < 4; ++i) eB[i] = __builtin_nontemporal_load(&row[lane + i * 64]);
        }
        {   // process row k (eA)
            float p = 0.f;
            #pragma unroll
            for (int i = 0; i < 4; ++i) p += dot4v(q4[i], eA[i]);
            p = wave_reduce_sum(p);
            msc = (lane == k) ? p : msc;
            const float mn = fmaxf(m, p);
            const float sc = __expf(m - mn);
            const float w  = __expf(p - mn);
            l = l * sc + w;
            #pragma unroll
            for (int i = 0; i < 4; ++i) a4[i] = a4[i] * sc + w * eA[i];
            m = mn;
        }
        if (k + 2 < 16) {  // prefetch row k+2 into eA
            const vf4* row = encb + (size_t)(wid + 4 * (k + 2)) * (DD / 4);
            #pragma unroll
            for (int i = 0; i < 4; ++i) eA[i] = __builtin_nontemporal_load(&row[lane + i * 64]);
        }
        {   // process row k+1 (eB)
            float p = 0.f;
            #pragma unroll
            for (int i = 0; i < 4; ++i) p += dot4v(q4[i], eB[i]);
            p = wave_reduce_sum(p);
            msc = (lane == (k + 1)) ? p : msc;
            const float mn = fmaxf(m, p);
            const float sc = __expf(m - mn);
            const float w  = __expf(p - mn);
            l = l * sc + w;
            #pragma unroll
            for (int i = 0; i < 4; ++i) a4[i] = a4[i] * sc + w * eB[i];
            m = mn;
        }
    }

    // scores: lane k holds row wid + 4k's raw score
    if (lane < 16) scores[(size_t)b * SS + s0 + wid + lane * 4] = msc;

    // block combine: 1 barrier, LDS per-wave partials
    __shared__ float m_s[4], l_s[4];
    __shared__ vf4 wacc[4][DD / 4];
    if (lane == 0) { m_s[wid] = m; l_s[wid] = l; }
    #pragma unroll
    for (int i = 0; i < 4; ++i) wacc[wid][lane + i * 64] = a4[i];
    __syncthreads();
    const float m_b = fmaxf(fmaxf(m_s[0], m_s[1]), fmaxf(m_s[2], m_s[3]));
    const float f0 = __expf(m_s[0] - m_b), f1 = __expf(m_s[1] - m_b);
    const float f2 = __expf(m_s[2] - m_b), f3 = __expf(m_s[3] - m_b);
    const float l_b = l_s[0] * f0 + l_s[1] * f1 + l_s[2] * f2 + l_s[3] * f3;
    const int t = threadIdx.x;
    const vf4 s = wacc[0][t] * f0 + wacc[1][t] * f1 + wacc[2][t] * f2 + wacc[3][t] * f3;
    ((vf4*)(pacc + (size_t)blockIdx.x * DD))[t] = s;
    if (t == 0) {
        pml[(size_t)blockIdx.x * 2 + 0] = m_b;
        pml[(size_t)blockIdx.x * 2 + 1] = l_b;
    }
}

// K3: combine chunk partials -> weighted[b,:], global (m,l) per b. 128 blocks x 64 thr.
__global__ __launch_bounds__(64) void k3_combine(const float* __restrict__ pacc,
                                                 const float* __restrict__ pml,
                                                 float* __restrict__ weighted,
                                                 float* __restrict__ mlglob) {
    const int b = blockIdx.x >> 2, qtr = blockIdx.x & 3;
    const int col = qtr * 64 + threadIdx.x;   // float4 column 0..255
    float mg = -1e30f;
    #pragma unroll 8
    for (int c = 0; c < CHUNKS; ++c) mg = fmaxf(mg, pml[(size_t)(b * CHUNKS + c) * 2]);
    float lg = 0.f;
    #pragma unroll 8
    for (int c = 0; c < CHUNKS; ++c)
        lg += pml[(size_t)(b * CHUNKS + c) * 2 + 1] * __expf(pml[(size_t)(b * CHUNKS + c) * 2] - mg);
    vf4 acc = (vf4)(0.f);
    #pragma unroll 4
    for (int c = 0; c < CHUNKS; ++c) {
        const float f = __expf(pml[(size_t)(b * CHUNKS + c) * 2] - mg);
        const vf4 v = ((const vf4*)(pacc + (size_t)(b * CHUNKS + c) * DD))[col];
        acc += f * v;
    }
    const float inv = 1.f / lg;
    ((vf4*)(weighted + (size_t)b * DD))[col] = acc * inv;
    if (qtr == 0 && threadIdx.x == 0) { mlglob[b * 2] = mg; mlglob[b * 2 + 1] = lg; }
}

// K4: normalize raw scores in place -> softmax weights output.
__global__ __launch_bounds__(256) void k4_norm(float* __restrict__ wts,
                                               const float* __restrict__ mlglob) {
    const int idx = blockIdx.x * 256 + threadIdx.x;  // B*S total
    const int b = idx >> 12;                          // / 4096
    const float mg = mlglob[b * 2], lg = mlglob[b * 2 + 1];
    wts[idx] = __expf(wts[idx] - mg) / lg;
}

// K5: out[b,d] = tanh( [weighted, dec] . Wout[d,:] ), Wout row-major [D, 2D]
__global__ __launch_bounds__(256) void k5_out(const float* __restrict__ weighted,
                                              const float* __restrict__ dec,
                                              const float* __restrict__ Wout,
                                              float* __restrict__ out) {
    const int wid = threadIdx.x >> 6, lane = threadIdx.x & 63;
    const int d = blockIdx.x * 4 + wid;  // 256 blocks -> 1024 d
    const vf4* Wrow = (const vf4*)(Wout + (size_t)d * (2 * DD));
    vf4 w4[8];
    #pragma unroll
    for (int i = 0; i < 8; ++i) w4[i] = Wrow[lane + i * 64];
    #pragma unroll 2
    for (int b = 0; b < BB; ++b) {
        const vf4* xw = (const vf4*)(weighted + (size_t)b * DD);
        const vf4* xd = (const vf4*)(dec + (size_t)b * DD);
        float p = 0.f;
        #pragma unroll
        for (int i = 0; i < 4; ++i) p += dot4v(w4[i], xw[lane + i * 64]);
        #pragma unroll
        for (int i = 0; i < 4; ++i) p += dot4v(w4[i + 4], xd[lane + i * 64]);
        p = wave_reduce_sum(p);
        if (lane == 0) out[(size_t)b * DD + d] = tanhf(p);
    }
}

extern "C" void kernel_launch(void* const* d_in, const int* in_sizes, int n_in,
                              void* d_out, int out_size, void* d_ws, size_t ws_size,
                              hipStream_t stream) {
    (void)in_sizes; (void)n_in; (void)out_size; (void)ws_size;
    const float* dec  = (const float*)d_in[0];   // [B, D]
    const float* enc  = (const float*)d_in[1];   // [B, S, D]
    const float* Win  = (const float*)d_in[2];   // [D, D]
    const float* Wout = (const float*)d_in[3];   // [D, 2D]

    float* out_final = (float*)d_out;                // [B, D]
    float* out_wts   = out_final + (size_t)BB * DD;  // [B, S]

    // workspace layout (floats)
    float* ws       = (float*)d_ws;
    float* dec_att  = ws;                                 // B*D
    float* pacc     = dec_att + (size_t)BB * DD;          // NBLK2*D
    float* pml      = pacc + (size_t)NBLK2 * DD;          // NBLK2*2
    float* weighted = pml + (size_t)NBLK2 * 2;            // B*D
    float* mlglob   = weighted + (size_t)BB * DD;         // B*2

    hipLaunchKernelGGL(k1_decatt, dim3(DD / 4), dim3(256), 0, stream, dec, Win, dec_att);
    hipLaunchKernelGGL(k2_scan, dim3(NBLK2), dim3(256), 0, stream, enc, dec_att, out_wts, pacc, pml);
    hipLaunchKernelGGL(k3_combine, dim3(BB * 4), dim3(64), 0, stream, pacc, pml, weighted, mlglob);
    hipLaunchKernelGGL(k4_norm, dim3(BB * SS / 256), dim3(256), 0, stream, out_wts, mlglob);
    hipLaunchKernelGGL(k5_out, dim3(DD / 4), dim3(256), 0, stream, weighted, dec, Wout, out_final);
}

// Round 3
// 173.607 us; speedup vs baseline: 1.5657x; 1.5657x over previous
//
#include <hip/hip_runtime.h>
#include <math.h>

#define BB 32
#define SS 4096
#define DD 1024
#define CHUNKS 64                      // S-chunks per batch
#define ROWS_PER_CHUNK (SS / CHUNKS)   // 64
#define NBLK2 (BB * CHUNKS)            // 2048

typedef float vf4 __attribute__((ext_vector_type(4)));

__device__ __forceinline__ float wave_reduce_sum(float v) {
    #pragma unroll
    for (int off = 32; off > 0; off >>= 1)
        v += __shfl_xor(v, off, 64);
    return v;
}

__device__ __forceinline__ float dot4v(vf4 a, vf4 b) {
    return a.x * b.x + a.y * b.y + a.z * b.z + a.w * b.w;
}

// K1: dec_att[b,d] = sum_k dec[b,k] * Win[d,k]   (x @ W.T)
__global__ __launch_bounds__(256) void k1_decatt(const float* __restrict__ dec,
                                                 const float* __restrict__ Win,
                                                 float* __restrict__ dec_att) {
    const int wid = threadIdx.x >> 6, lane = threadIdx.x & 63;
    const int d = blockIdx.x * 4 + wid;          // 256 blocks -> 1024 d
    const vf4* Wrow = (const vf4*)(Win + (size_t)d * DD);
    vf4 w4[4];
    #pragma unroll
    for (int i = 0; i < 4; ++i) w4[i] = Wrow[lane + i * 64];
    #pragma unroll 2
    for (int b = 0; b < BB; ++b) {
        const vf4* x = (const vf4*)(dec + (size_t)b * DD);
        float p = 0.f;
        #pragma unroll
        for (int i = 0; i < 4; ++i) p += dot4v(w4[i], x[lane + i * 64]);
        p = wave_reduce_sum(p);
        if (lane == 0) dec_att[(size_t)b * DD + d] = p;
    }
}

// K2: single-pass online-softmax scan, 4 rows per step (batched reduce for ILP).
// Wave wid owns rows [wid*16, wid*16+16) of its 64-row chunk.
__global__ __launch_bounds__(256) void k2_scan(const float* __restrict__ enc,
                                               const float* __restrict__ dec_att,
                                               float* __restrict__ scores,
                                               float* __restrict__ pacc,
                                               float* __restrict__ pml) {
    const int wid = threadIdx.x >> 6, lane = threadIdx.x & 63;
    const int b = blockIdx.x / CHUNKS, chunk = blockIdx.x % CHUNKS;
    const int s0 = chunk * ROWS_PER_CHUNK;

    const vf4* q = (const vf4*)(dec_att + (size_t)b * DD);
    vf4 q4[4];
    #pragma unroll
    for (int i = 0; i < 4; ++i) q4[i] = q[lane + i * 64];

    const vf4* encb = (const vf4*)(enc + ((size_t)b * SS + s0) * DD);

    float m = -1e30f, l = 0.f;
    vf4 a4[4];
    #pragma unroll
    for (int i = 0; i < 4; ++i) a4[i] = (vf4)(0.f);

    #pragma unroll 1
    for (int g = 0; g < 4; ++g) {
        const int r0 = wid * 16 + g * 4;
        // load 4 rows (16 KB per wave)
        vf4 e[4][4];
        #pragma unroll
        for (int j = 0; j < 4; ++j) {
            const vf4* row = encb + (size_t)(r0 + j) * (DD / 4);
            #pragma unroll
            for (int i = 0; i < 4; ++i) e[j][i] = row[lane + i * 64];
        }
        // 4 partial dots
        float p[4];
        #pragma unroll
        for (int j = 0; j < 4; ++j) {
            float s = 0.f;
            #pragma unroll
            for (int i = 0; i < 4; ++i) s += dot4v(q4[i], e[j][i]);
            p[j] = s;
        }
        // 4 independent butterfly reductions, interleaved (ILP)
        #pragma unroll
        for (int off = 32; off > 0; off >>= 1) {
            #pragma unroll
            for (int j = 0; j < 4; ++j) p[j] += __shfl_xor(p[j], off, 64);
        }
        // raw scores: one vf4 store per group
        if (lane == 0) {
            vf4 st; st.x = p[0]; st.y = p[1]; st.z = p[2]; st.w = p[3];
            *(vf4*)(scores + (size_t)b * SS + s0 + r0) = st;
        }
        // one max/rescale per 4 rows
        const float mn = fmaxf(fmaxf(fmaxf(m, p[0]), fmaxf(p[1], p[2])), p[3]);
        const float sc = __expf(m - mn);
        float w[4];
        #pragma unroll
        for (int j = 0; j < 4; ++j) w[j] = __expf(p[j] - mn);
        l = l * sc + w[0] + w[1] + w[2] + w[3];
        #pragma unroll
        for (int i = 0; i < 4; ++i)
            a4[i] = a4[i] * sc + w[0] * e[0][i] + w[1] * e[1][i]
                               + w[2] * e[2][i] + w[3] * e[3][i];
        m = mn;
    }

    // block combine: 1 barrier, LDS per-wave partials
    __shared__ float m_s[4], l_s[4];
    __shared__ vf4 wacc[4][DD / 4];
    if (lane == 0) { m_s[wid] = m; l_s[wid] = l; }
    #pragma unroll
    for (int i = 0; i < 4; ++i) wacc[wid][lane + i * 64] = a4[i];
    __syncthreads();
    const float m_b = fmaxf(fmaxf(m_s[0], m_s[1]), fmaxf(m_s[2], m_s[3]));
    const float f0 = __expf(m_s[0] - m_b), f1 = __expf(m_s[1] - m_b);
    const float f2 = __expf(m_s[2] - m_b), f3 = __expf(m_s[3] - m_b);
    const float l_b = l_s[0] * f0 + l_s[1] * f1 + l_s[2] * f2 + l_s[3] * f3;
    const int t = threadIdx.x;
    const vf4 s = wacc[0][t] * f0 + wacc[1][t] * f1 + wacc[2][t] * f2 + wacc[3][t] * f3;
    ((vf4*)(pacc + (size_t)blockIdx.x * DD))[t] = s;
    if (t == 0) {
        pml[(size_t)blockIdx.x * 2 + 0] = m_b;
        pml[(size_t)blockIdx.x * 2 + 1] = l_b;
    }
}

// K3: combine chunk partials -> weighted[b,:], global (m,l) per b. 128 blocks x 64 thr.
__global__ __launch_bounds__(64) void k3_combine(const float* __restrict__ pacc,
                                                 const float* __restrict__ pml,
                                                 float* __restrict__ weighted,
                                                 float* __restrict__ mlglob) {
    const int b = blockIdx.x >> 2, qtr = blockIdx.x & 3;
    const int col = qtr * 64 + threadIdx.x;   // float4 column 0..255
    float mg = -1e30f;
    #pragma unroll 8
    for (int c = 0; c < CHUNKS; ++c) mg = fmaxf(mg, pml[(size_t)(b * CHUNKS + c) * 2]);
    float lg = 0.f;
    #pragma unroll 8
    for (int c = 0; c < CHUNKS; ++c)
        lg += pml[(size_t)(b * CHUNKS + c) * 2 + 1] * __expf(pml[(size_t)(b * CHUNKS + c) * 2] - mg);
    vf4 acc = (vf4)(0.f);
    #pragma unroll 4
    for (int c = 0; c < CHUNKS; ++c) {
        const float f = __expf(pml[(size_t)(b * CHUNKS + c) * 2] - mg);
        const vf4 v = ((const vf4*)(pacc + (size_t)(b * CHUNKS + c) * DD))[col];
        acc += f * v;
    }
    const float inv = 1.f / lg;
    ((vf4*)(weighted + (size_t)b * DD))[col] = acc * inv;
    if (qtr == 0 && threadIdx.x == 0) { mlglob[b * 2] = mg; mlglob[b * 2 + 1] = lg; }
}

// K4: normalize raw scores in place -> softmax weights output.
__global__ __launch_bounds__(256) void k4_norm(float* __restrict__ wts,
                                               const float* __restrict__ mlglob) {
    const int idx = blockIdx.x * 256 + threadIdx.x;  // B*S total
    const int b = idx >> 12;                          // / 4096
    const float mg = mlglob[b * 2], lg = mlglob[b * 2 + 1];
    wts[idx] = __expf(wts[idx] - mg) / lg;
}

// K5: out[b,d] = tanh( [weighted, dec] . Wout[d,:] ), Wout row-major [D, 2D]
__global__ __launch_bounds__(256) void k5_out(const float* __restrict__ weighted,
                                              const float* __restrict__ dec,
                                              const float* __restrict__ Wout,
                                              float* __restrict__ out) {
    const int wid = threadIdx.x >> 6, lane = threadIdx.x & 63;
    const int d = blockIdx.x * 4 + wid;  // 256 blocks -> 1024 d
    const vf4* Wrow = (const vf4*)(Wout + (size_t)d * (2 * DD));
    vf4 w4[8];
    #pragma unroll
    for (int i = 0; i < 8; ++i) w4[i] = Wrow[lane + i * 64];
    #pragma unroll 2
    for (int b = 0; b < BB; ++b) {
        const vf4* xw = (const vf4*)(weighted + (size_t)b * DD);
        const vf4* xd = (const vf4*)(dec + (size_t)b * DD);
        float p = 0.f;
        #pragma unroll
        for (int i = 0; i < 4; ++i) p += dot4v(w4[i], xw[lane + i * 64]);
        #pragma unroll
        for (int i = 0; i < 4; ++i) p += dot4v(w4[i + 4], xd[lane + i * 64]);
        p = wave_reduce_sum(p);
        if (lane == 0) out[(size_t)b * DD + d] = tanhf(p);
    }
}

extern "C" void kernel_launch(void* const* d_in, const int* in_sizes, int n_in,
                              void* d_out, int out_size, void* d_ws, size_t ws_size,
                              hipStream_t stream) {
    (void)in_sizes; (void)n_in; (void)out_size; (void)ws_size;
    const float* dec  = (const float*)d_in[0];   // [B, D]
    const float* enc  = (const float*)d_in[1];   // [B, S, D]
    const float* Win  = (const float*)d_in[2];   // [D, D]
    const float* Wout = (const float*)d_in[3];   // [D, 2D]

    float* out_final = (float*)d_out;                // [B, D]
    float* out_wts   = out_final + (size_t)BB * DD;  // [B, S]

    // workspace layout (floats)
    float* ws       = (float*)d_ws;
    float* dec_att  = ws;                                 // B*D
    float* pacc     = dec_att + (size_t)BB * DD;          // NBLK2*D
    float* pml      = pacc + (size_t)NBLK2 * DD;          // NBLK2*2
    float* weighted = pml + (size_t)NBLK2 * 2;            // B*D
    float* mlglob   = weighted + (size_t)BB * DD;         // B*2

    hipLaunchKernelGGL(k1_decatt, dim3(DD / 4), dim3(256), 0, stream, dec, Win, dec_att);
    hipLaunchKernelGGL(k2_scan, dim3(NBLK2), dim3(256), 0, stream, enc, dec_att, out_wts, pacc, pml);
    hipLaunchKernelGGL(k3_combine, dim3(BB * 4), dim3(64), 0, stream, pacc, pml, weighted, mlglob);
    hipLaunchKernelGGL(k4_norm, dim3(BB * SS / 256), dim3(256), 0, stream, out_wts, mlglob);
    hipLaunchKernelGGL(k5_out, dim3(DD / 4), dim3(256), 0, stream, weighted, dec, Wout, out_final);
}

// Round 4
// 167.246 us; speedup vs baseline: 1.6253x; 1.0380x over previous
//
#include <hip/hip_runtime.h>
#include <math.h>

#define BB 32
#define SS 4096
#define DD 1024
#define CHUNKS 64                      // S-chunks per batch
#define ROWS_PER_CHUNK (SS / CHUNKS)   // 64
#define NBLK2 (BB * CHUNKS)            // 2048

typedef float vf4 __attribute__((ext_vector_type(4)));

__device__ __forceinline__ float wave_reduce_sum(float v) {
    #pragma unroll
    for (int off = 32; off > 0; off >>= 1)
        v += __shfl_xor(v, off, 64);
    return v;
}

__device__ __forceinline__ float dot4v(vf4 a, vf4 b) {
    return a.x * b.x + a.y * b.y + a.z * b.z + a.w * b.w;
}

// K1: dec_att[b,d] = sum_k dec[b,k] * Win[d,k]   (x @ W.T), 4 b's per reduce group
__global__ __launch_bounds__(256) void k1_decatt(const float* __restrict__ dec,
                                                 const float* __restrict__ Win,
                                                 float* __restrict__ dec_att) {
    const int wid = threadIdx.x >> 6, lane = threadIdx.x & 63;
    const int d = blockIdx.x * 4 + wid;          // 256 blocks -> 1024 d
    const vf4* Wrow = (const vf4*)(Win + (size_t)d * DD);
    vf4 w4[4];
    #pragma unroll
    for (int i = 0; i < 4; ++i) w4[i] = Wrow[lane + i * 64];
    #pragma unroll 1
    for (int bg = 0; bg < 8; ++bg) {
        float p[4] = {0.f, 0.f, 0.f, 0.f};
        #pragma unroll
        for (int j = 0; j < 4; ++j) {
            const vf4* x = (const vf4*)(dec + (size_t)(bg * 4 + j) * DD);
            #pragma unroll
            for (int i = 0; i < 4; ++i) p[j] += dot4v(w4[i], x[lane + i * 64]);
        }
        #pragma unroll
        for (int off = 32; off > 0; off >>= 1) {
            #pragma unroll
            for (int j = 0; j < 4; ++j) p[j] += __shfl_xor(p[j], off, 64);
        }
        if (lane == 0) {
            #pragma unroll
            for (int j = 0; j < 4; ++j)
                dec_att[(size_t)(bg * 4 + j) * DD + d] = p[j];
        }
    }
}

// K2: single-pass online-softmax scan, 8 rows (32 KB) per group.
// Wave wid owns rows [wid*16, wid*16+16) of its 64-row chunk; 2 groups.
__global__ __launch_bounds__(256) void k2_scan(const float* __restrict__ enc,
                                               const float* __restrict__ dec_att,
                                               float* __restrict__ scores,
                                               float* __restrict__ pacc,
                                               float* __restrict__ pml) {
    const int wid = threadIdx.x >> 6, lane = threadIdx.x & 63;
    const int b = blockIdx.x / CHUNKS, chunk = blockIdx.x % CHUNKS;
    const int s0 = chunk * ROWS_PER_CHUNK;

    const vf4* q = (const vf4*)(dec_att + (size_t)b * DD);
    vf4 q4[4];
    #pragma unroll
    for (int i = 0; i < 4; ++i) q4[i] = q[lane + i * 64];

    const vf4* encb = (const vf4*)(enc + ((size_t)b * SS + s0) * DD);

    float m = -1e30f, l = 0.f;
    vf4 a4[4];
    #pragma unroll
    for (int i = 0; i < 4; ++i) a4[i] = (vf4)(0.f);

    #pragma unroll 1
    for (int g = 0; g < 2; ++g) {
        const int r0 = wid * 16 + g * 8;
        // load 8 rows (32 KB per wave) as one long burst
        vf4 e[8][4];
        #pragma unroll
        for (int j = 0; j < 8; ++j) {
            const vf4* row = encb + (size_t)(r0 + j) * (DD / 4);
            #pragma unroll
            for (int i = 0; i < 4; ++i) e[j][i] = row[lane + i * 64];
        }
        // 8 partial dots
        float p[8];
        #pragma unroll
        for (int j = 0; j < 8; ++j) {
            float s = 0.f;
            #pragma unroll
            for (int i = 0; i < 4; ++i) s += dot4v(q4[i], e[j][i]);
            p[j] = s;
        }
        // 8 independent butterfly reductions, interleaved (ILP)
        #pragma unroll
        for (int off = 32; off > 0; off >>= 1) {
            #pragma unroll
            for (int j = 0; j < 8; ++j) p[j] += __shfl_xor(p[j], off, 64);
        }
        // raw scores: two vf4 stores per group
        if (lane == 0) {
            vf4 st0, st1;
            st0.x = p[0]; st0.y = p[1]; st0.z = p[2]; st0.w = p[3];
            st1.x = p[4]; st1.y = p[5]; st1.z = p[6]; st1.w = p[7];
            *(vf4*)(scores + (size_t)b * SS + s0 + r0) = st0;
            *(vf4*)(scores + (size_t)b * SS + s0 + r0 + 4) = st1;
        }
        // one max/rescale per 8 rows
        float mp = p[0];
        #pragma unroll
        for (int j = 1; j < 8; ++j) mp = fmaxf(mp, p[j]);
        const float mn = fmaxf(m, mp);
        const float sc = __expf(m - mn);
        float w[8];
        #pragma unroll
        for (int j = 0; j < 8; ++j) w[j] = __expf(p[j] - mn);
        float lsum = 0.f;
        #pragma unroll
        for (int j = 0; j < 8; ++j) lsum += w[j];
        l = l * sc + lsum;
        #pragma unroll
        for (int i = 0; i < 4; ++i) {
            vf4 acc = a4[i] * sc;
            #pragma unroll
            for (int j = 0; j < 8; ++j) acc += w[j] * e[j][i];
            a4[i] = acc;
        }
        m = mn;
    }

    // block combine: 1 barrier, LDS per-wave partials
    __shared__ float m_s[4], l_s[4];
    __shared__ vf4 wacc[4][DD / 4];
    if (lane == 0) { m_s[wid] = m; l_s[wid] = l; }
    #pragma unroll
    for (int i = 0; i < 4; ++i) wacc[wid][lane + i * 64] = a4[i];
    __syncthreads();
    const float m_b = fmaxf(fmaxf(m_s[0], m_s[1]), fmaxf(m_s[2], m_s[3]));
    const float f0 = __expf(m_s[0] - m_b), f1 = __expf(m_s[1] - m_b);
    const float f2 = __expf(m_s[2] - m_b), f3 = __expf(m_s[3] - m_b);
    const float l_b = l_s[0] * f0 + l_s[1] * f1 + l_s[2] * f2 + l_s[3] * f3;
    const int t = threadIdx.x;
    const vf4 s = wacc[0][t] * f0 + wacc[1][t] * f1 + wacc[2][t] * f2 + wacc[3][t] * f3;
    ((vf4*)(pacc + (size_t)blockIdx.x * DD))[t] = s;
    if (t == 0) {
        pml[(size_t)blockIdx.x * 2 + 0] = m_b;
        pml[(size_t)blockIdx.x * 2 + 1] = l_b;
    }
}

// K3: combine chunk partials -> weighted[b,:], global (m,l) per b. 128 blocks x 64 thr.
__global__ __launch_bounds__(64) void k3_combine(const float* __restrict__ pacc,
                                                 const float* __restrict__ pml,
                                                 float* __restrict__ weighted,
                                                 float* __restrict__ mlglob) {
    const int b = blockIdx.x >> 2, qtr = blockIdx.x & 3;
    const int col = qtr * 64 + threadIdx.x;   // float4 column 0..255
    float mg = -1e30f;
    #pragma unroll 8
    for (int c = 0; c < CHUNKS; ++c) mg = fmaxf(mg, pml[(size_t)(b * CHUNKS + c) * 2]);
    float lg = 0.f;
    #pragma unroll 8
    for (int c = 0; c < CHUNKS; ++c)
        lg += pml[(size_t)(b * CHUNKS + c) * 2 + 1] * __expf(pml[(size_t)(b * CHUNKS + c) * 2] - mg);
    vf4 acc = (vf4)(0.f);
    #pragma unroll 4
    for (int c = 0; c < CHUNKS; ++c) {
        const float f = __expf(pml[(size_t)(b * CHUNKS + c) * 2] - mg);
        const vf4 v = ((const vf4*)(pacc + (size_t)(b * CHUNKS + c) * DD))[col];
        acc += f * v;
    }
    const float inv = 1.f / lg;
    ((vf4*)(weighted + (size_t)b * DD))[col] = acc * inv;
    if (qtr == 0 && threadIdx.x == 0) { mlglob[b * 2] = mg; mlglob[b * 2 + 1] = lg; }
}

// K4: normalize raw scores in place -> softmax weights output.
__global__ __launch_bounds__(256) void k4_norm(float* __restrict__ wts,
                                               const float* __restrict__ mlglob) {
    const int idx = blockIdx.x * 256 + threadIdx.x;  // B*S total
    const int b = idx >> 12;                          // / 4096
    const float mg = mlglob[b * 2], lg = mlglob[b * 2 + 1];
    wts[idx] = __expf(wts[idx] - mg) / lg;
}

// K5: out[b,d] = tanh( [weighted, dec] . Wout[d,:] ), Wout row-major [D, 2D]
__global__ __launch_bounds__(256) void k5_out(const float* __restrict__ weighted,
                                              const float* __restrict__ dec,
                                              const float* __restrict__ Wout,
                                              float* __restrict__ out) {
    const int wid = threadIdx.x >> 6, lane = threadIdx.x & 63;
    const int d = blockIdx.x * 4 + wid;  // 256 blocks -> 1024 d
    const vf4* Wrow = (const vf4*)(Wout + (size_t)d * (2 * DD));
    vf4 w4[8];
    #pragma unroll
    for (int i = 0; i < 8; ++i) w4[i] = Wrow[lane + i * 64];
    #pragma unroll 2
    for (int b = 0; b < BB; ++b) {
        const vf4* xw = (const vf4*)(weighted + (size_t)b * DD);
        const vf4* xd = (const vf4*)(dec + (size_t)b * DD);
        float p = 0.f;
        #pragma unroll
        for (int i = 0; i < 4; ++i) p += dot4v(w4[i], xw[lane + i * 64]);
        #pragma unroll
        for (int i = 0; i < 4; ++i) p += dot4v(w4[i + 4], xd[lane + i * 64]);
        p = wave_reduce_sum(p);
        if (lane == 0) out[(size_t)b * DD + d] = tanhf(p);
    }
}

extern "C" void kernel_launch(void* const* d_in, const int* in_sizes, int n_in,
                              void* d_out, int out_size, void* d_ws, size_t ws_size,
                              hipStream_t stream) {
    (void)in_sizes; (void)n_in; (void)out_size; (void)ws_size;
    const float* dec  = (const float*)d_in[0];   // [B, D]
    const float* enc  = (const float*)d_in[1];   // [B, S, D]
    const float* Win  = (const float*)d_in[2];   // [D, D]
    const float* Wout = (const float*)d_in[3];   // [D, 2D]

    float* out_final = (float*)d_out;                // [B, D]
    float* out_wts   = out_final + (size_t)BB * DD;  // [B, S]

    // workspace layout (floats)
    float* ws       = (float*)d_ws;
    float* dec_att  = ws;                                 // B*D
    float* pacc     = dec_att + (size_t)BB * DD;          // NBLK2*D
    float* pml      = pacc + (size_t)NBLK2 * DD;          // NBLK2*2
    float* weighted = pml + (size_t)NBLK2 * 2;            // B*D
    float* mlglob   = weighted + (size_t)BB * DD;         // B*2

    hipLaunchKernelGGL(k1_decatt, dim3(DD / 4), dim3(256), 0, stream, dec, Win, dec_att);
    hipLaunchKernelGGL(k2_scan, dim3(NBLK2), dim3(256), 0, stream, enc, dec_att, out_wts, pacc, pml);
    hipLaunchKernelGGL(k3_combine, dim3(BB * 4), dim3(64), 0, stream, pacc, pml, weighted, mlglob);
    hipLaunchKernelGGL(k4_norm, dim3(BB * SS / 256), dim3(256), 0, stream, out_wts, mlglob);
    hipLaunchKernelGGL(k5_out, dim3(DD / 4), dim3(256), 0, stream, weighted, dec, Wout, out_final);
}

// Round 5
// 157.581 us; speedup vs baseline: 1.7250x; 1.0613x over previous
//
#include <hip/hip_runtime.h>
#include <math.h>

#define BB 32
#define SS 4096
#define DD 1024
#define SEGS 32                        // segments per batch
#define ROWS_PER_SEG (SS / SEGS)       // 128
#define GROUPS (ROWS_PER_SEG / 8)      // 16 groups of 8 rows
#define NBLK2 (BB * SEGS)              // 1024

typedef float vf4 __attribute__((ext_vector_type(4)));

__device__ __forceinline__ float wave_reduce_sum(float v) {
    #pragma unroll
    for (int off = 32; off > 0; off >>= 1)
        v += __shfl_xor(v, off, 64);
    return v;
}

__device__ __forceinline__ float dot4f(float4 a, float4 b) {
    return a.x * b.x + a.y * b.y + a.z * b.z + a.w * b.w;
}

__device__ __forceinline__ float dot4v(vf4 a, vf4 b) {
    return a.x * b.x + a.y * b.y + a.z * b.z + a.w * b.w;
}

// K1: dec_att[b,d] = sum_k dec[b,k] * Win[d,k]   (x @ W.T), 4 b's per reduce group
__global__ __launch_bounds__(256) void k1_decatt(const float* __restrict__ dec,
                                                 const float* __restrict__ Win,
                                                 float* __restrict__ dec_att) {
    const int wid = threadIdx.x >> 6, lane = threadIdx.x & 63;
    const int d = blockIdx.x * 4 + wid;          // 256 blocks -> 1024 d
    const vf4* Wrow = (const vf4*)(Win + (size_t)d * DD);
    vf4 w4[4];
    #pragma unroll
    for (int i = 0; i < 4; ++i) w4[i] = Wrow[lane + i * 64];
    #pragma unroll 1
    for (int bg = 0; bg < 8; ++bg) {
        float p[4] = {0.f, 0.f, 0.f, 0.f};
        #pragma unroll
        for (int j = 0; j < 4; ++j) {
            const vf4* x = (const vf4*)(dec + (size_t)(bg * 4 + j) * DD);
            #pragma unroll
            for (int i = 0; i < 4; ++i) p[j] += dot4v(w4[i], x[lane + i * 64]);
        }
        #pragma unroll
        for (int off = 32; off > 0; off >>= 1) {
            #pragma unroll
            for (int j = 0; j < 4; ++j) p[j] += __shfl_xor(p[j], off, 64);
        }
        if (lane == 0) {
            #pragma unroll
            for (int j = 0; j < 4; ++j)
                dec_att[(size_t)(bg * 4 + j) * DD + d] = p[j];
        }
    }
}

// K2: single-pass online-softmax scan, block-column-split.
// 256 threads x 4 cols each; 8-row groups with cross-fence register prefetch.
// Raw s_barrier (lgkmcnt-only) keeps prefetch loads in flight across the
// reduce fence. Per-thread column accumulator -> no block combine at end.
__global__ __launch_bounds__(256) void k2_scan(const float* __restrict__ enc,
                                               const float* __restrict__ dec_att,
                                               float* __restrict__ scores,
                                               float* __restrict__ pacc,
                                               float* __restrict__ pml) {
    const int tid = threadIdx.x;
    const int wid = tid >> 6, lane = tid & 63;
    const int b = blockIdx.x / SEGS, seg = blockIdx.x % SEGS;
    const int s0 = seg * ROWS_PER_SEG;

    // thread's 4 columns
    const float4* encc = (const float4*)(enc + ((size_t)b * SS + s0) * DD) + tid;
    const float4 q4 = ((const float4*)(dec_att + (size_t)b * DD))[tid];
    float* scores_row = scores + (size_t)b * SS + s0;

    float4 a4 = make_float4(0.f, 0.f, 0.f, 0.f);
    float m = -1e30f, l = 0.f;

    __shared__ __align__(16) float lds_p[2][8][4];   // [buf][row][wave]

    float4 eC[8], eN[8];
    #pragma unroll
    for (int j = 0; j < 8; ++j) eC[j] = encc[(size_t)j * (DD / 4)];

    auto process = [&](int g, const float4* e) {
        float p[8];
        #pragma unroll
        for (int j = 0; j < 8; ++j) p[j] = dot4f(q4, e[j]);
        // 8 interleaved 64-lane butterflies
        #pragma unroll
        for (int off = 32; off > 0; off >>= 1) {
            #pragma unroll
            for (int j = 0; j < 8; ++j) p[j] += __shfl_xor(p[j], off, 64);
        }
        if (lane == 0) {
            #pragma unroll
            for (int j = 0; j < 8; ++j) lds_p[g & 1][j][wid] = p[j];
        }
        // LDS-visibility only; do NOT drain vmcnt (prefetch stays in flight)
        asm volatile("s_waitcnt lgkmcnt(0)" ::: "memory");
        __builtin_amdgcn_s_barrier();
        float s[8];
        #pragma unroll
        for (int j = 0; j < 8; ++j) {
            const float4 v = *(const float4*)&lds_p[g & 1][j][0];
            s[j] = (v.x + v.y) + (v.z + v.w);
        }
        if (tid == 0) {
            #pragma unroll
            for (int j = 0; j < 8; ++j) scores_row[g * 8 + j] = s[j];
        }
        float mp = s[0];
        #pragma unroll
        for (int j = 1; j < 8; ++j) mp = fmaxf(mp, s[j]);
        const float mn = fmaxf(m, mp);
        const float sc = __expf(m - mn);
        float w[8], lsum = 0.f;
        #pragma unroll
        for (int j = 0; j < 8; ++j) { w[j] = __expf(s[j] - mn); lsum += w[j]; }
        l = l * sc + lsum;
        a4.x *= sc; a4.y *= sc; a4.z *= sc; a4.w *= sc;
        #pragma unroll
        for (int j = 0; j < 8; ++j) {
            a4.x += w[j] * e[j].x; a4.y += w[j] * e[j].y;
            a4.z += w[j] * e[j].z; a4.w += w[j] * e[j].w;
        }
        m = mn;
    };

    #pragma unroll 1
    for (int g = 0; g < GROUPS - 1; ++g) {
        // prefetch next group before this group's reduce fence
        #pragma unroll
        for (int j = 0; j < 8; ++j)
            eN[j] = encc[(size_t)((g + 1) * 8 + j) * (DD / 4)];
        process(g, eC);
        #pragma unroll
        for (int j = 0; j < 8; ++j) eC[j] = eN[j];
    }
    process(GROUPS - 1, eC);

    // epilogue: per-thread columns -> direct coalesced partial write
    ((float4*)(pacc + (size_t)blockIdx.x * DD))[tid] = a4;
    if (tid == 0) {
        pml[(size_t)blockIdx.x * 2 + 0] = m;
        pml[(size_t)blockIdx.x * 2 + 1] = l;
    }
}

// K3: combine seg partials -> weighted[b,:], global (m,l) per b. 128 blocks x 64 thr.
__global__ __launch_bounds__(64) void k3_combine(const float* __restrict__ pacc,
                                                 const float* __restrict__ pml,
                                                 float* __restrict__ weighted,
                                                 float* __restrict__ mlglob) {
    const int b = blockIdx.x >> 2, qtr = blockIdx.x & 3;
    const int col = qtr * 64 + threadIdx.x;   // float4 column 0..255
    float mg = -1e30f;
    #pragma unroll 8
    for (int c = 0; c < SEGS; ++c) mg = fmaxf(mg, pml[(size_t)(b * SEGS + c) * 2]);
    float lg = 0.f;
    #pragma unroll 8
    for (int c = 0; c < SEGS; ++c)
        lg += pml[(size_t)(b * SEGS + c) * 2 + 1] * __expf(pml[(size_t)(b * SEGS + c) * 2] - mg);
    vf4 acc = (vf4)(0.f);
    #pragma unroll 4
    for (int c = 0; c < SEGS; ++c) {
        const float f = __expf(pml[(size_t)(b * SEGS + c) * 2] - mg);
        const vf4 v = ((const vf4*)(pacc + (size_t)(b * SEGS + c) * DD))[col];
        acc += f * v;
    }
    const float inv = 1.f / lg;
    ((vf4*)(weighted + (size_t)b * DD))[col] = acc * inv;
    if (qtr == 0 && threadIdx.x == 0) { mlglob[b * 2] = mg; mlglob[b * 2 + 1] = lg; }
}

// K4: normalize raw scores in place -> softmax weights output.
__global__ __launch_bounds__(256) void k4_norm(float* __restrict__ wts,
                                               const float* __restrict__ mlglob) {
    const int idx = blockIdx.x * 256 + threadIdx.x;  // B*S total
    const int b = idx >> 12;                          // / 4096
    const float mg = mlglob[b * 2], lg = mlglob[b * 2 + 1];
    wts[idx] = __expf(wts[idx] - mg) / lg;
}

// K5: out[b,d] = tanh( [weighted, dec] . Wout[d,:] ), Wout row-major [D, 2D]
__global__ __launch_bounds__(256) void k5_out(const float* __restrict__ weighted,
                                              const float* __restrict__ dec,
                                              const float* __restrict__ Wout,
                                              float* __restrict__ out) {
    const int wid = threadIdx.x >> 6, lane = threadIdx.x & 63;
    const int d = blockIdx.x * 4 + wid;  // 256 blocks -> 1024 d
    const vf4* Wrow = (const vf4*)(Wout + (size_t)d * (2 * DD));
    vf4 w4[8];
    #pragma unroll
    for (int i = 0; i < 8; ++i) w4[i] = Wrow[lane + i * 64];
    #pragma unroll 2
    for (int b = 0; b < BB; ++b) {
        const vf4* xw = (const vf4*)(weighted + (size_t)b * DD);
        const vf4* xd = (const vf4*)(dec + (size_t)b * DD);
        float p = 0.f;
        #pragma unroll
        for (int i = 0; i < 4; ++i) p += dot4v(w4[i], xw[lane + i * 64]);
        #pragma unroll
        for (int i = 0; i < 4; ++i) p += dot4v(w4[i + 4], xd[lane + i * 64]);
        p = wave_reduce_sum(p);
        if (lane == 0) out[(size_t)b * DD + d] = tanhf(p);
    }
}

extern "C" void kernel_launch(void* const* d_in, const int* in_sizes, int n_in,
                              void* d_out, int out_size, void* d_ws, size_t ws_size,
                              hipStream_t stream) {
    (void)in_sizes; (void)n_in; (void)out_size; (void)ws_size;
    const float* dec  = (const float*)d_in[0];   // [B, D]
    const float* enc  = (const float*)d_in[1];   // [B, S, D]
    const float* Win  = (const float*)d_in[2];   // [D, D]
    const float* Wout = (const float*)d_in[3];   // [D, 2D]

    float* out_final = (float*)d_out;                // [B, D]
    float* out_wts   = out_final + (size_t)BB * DD;  // [B, S]

    // workspace layout (floats)
    float* ws       = (float*)d_ws;
    float* dec_att  = ws;                                 // B*D
    float* pacc     = dec_att + (size_t)BB * DD;          // NBLK2*D
    float* pml      = pacc + (size_t)NBLK2 * DD;          // NBLK2*2
    float* weighted = pml + (size_t)NBLK2 * 2;            // B*D
    float* mlglob   = weighted + (size_t)BB * DD;         // B*2

    hipLaunchKernelGGL(k1_decatt, dim3(DD / 4), dim3(256), 0, stream, dec, Win, dec_att);
    hipLaunchKernelGGL(k2_scan, dim3(NBLK2), dim3(256), 0, stream, enc, dec_att, out_wts, pacc, pml);
    hipLaunchKernelGGL(k3_combine, dim3(BB * 4), dim3(64), 0, stream, pacc, pml, weighted, mlglob);
    hipLaunchKernelGGL(k4_norm, dim3(BB * SS / 256), dim3(256), 0, stream, out_wts, mlglob);
    hipLaunchKernelGGL(k5_out, dim3(DD / 4), dim3(256), 0, stream, weighted, dec, Wout, out_final);
}